// Round 1
// baseline (2207.632 us; speedup 1.0000x reference)
//
#include <hip/hip_runtime.h>

// ChebConv(K=3) x3 on MI355X.
// Pipeline per layer: SpMM T1 = Lhat(H); SpMM T2 = 2*Lhat(T1) - H;
// GEMM out = relu([H|T1|T2] @ [W0;W1;W2] + b)  (bf16 MFMA, fp32 accum).
// All feature intermediates bf16 in padded ping-pong buffers:
//   CA: [50048][3*512]  (layers 1 and 3, Kpad=512)
//   CB: [50048][3*256]  (layer 2, Kpad=256)
// CSR (by dst) built once per call from edge_index.
// ws need: ~248 MB.

typedef unsigned short u16;
typedef __attribute__((ext_vector_type(8))) short s16x8;
typedef __attribute__((ext_vector_type(4))) float f32x4;
typedef __attribute__((ext_vector_type(8))) unsigned short u16x8;
typedef __attribute__((ext_vector_type(4))) unsigned short u16x4;

__device__ __forceinline__ float b2f(u16 u) {
  union { unsigned int i; float f; } x; x.i = ((unsigned int)u) << 16; return x.f;
}
__device__ __forceinline__ u16 f2b(float f) {  // round-to-nearest-even
  union { float f; unsigned int i; } x; x.f = f;
  unsigned int r = x.i + 0x7fffu + ((x.i >> 16) & 1u);
  return (u16)(r >> 16);
}

typedef __attribute__((address_space(1))) unsigned int gu32_t;
typedef __attribute__((address_space(3))) unsigned int lu32_t;
__device__ __forceinline__ void gload16(const void* g, void* l) {
  // async global->LDS, 16B per lane; LDS dest = wave-uniform base + lane*16
  __builtin_amdgcn_global_load_lds((const gu32_t*)g, (lu32_t*)l, 16, 0, 0);
}

// ----------------- CSR build -----------------
__global__ void k_zero_i32(int* p, int n) {
  int t = blockIdx.x * 256 + threadIdx.x;
  if (t < n) p[t] = 0;
}

__global__ void k_hist(const int* __restrict__ ei, int* __restrict__ cnt, int E) {
  int e = blockIdx.x * 256 + threadIdx.x;
  if (e < E) atomicAdd(&cnt[ei[E + e]], 1);  // ei[1][e] = dst
}

__global__ void k_dis(const int* __restrict__ cnt, float* __restrict__ dis, int N) {
  int t = blockIdx.x * 256 + threadIdx.x;
  if (t < N) dis[t] = cnt[t] > 0 ? rsqrtf((float)cnt[t]) : 0.f;
}

__global__ void k_scan1(const int* __restrict__ cnt, int* __restrict__ part, int N) {
  __shared__ int s[256];
  int t = threadIdx.x, idx = blockIdx.x * 256 + t;
  s[t] = idx < N ? cnt[idx] : 0;
  __syncthreads();
  for (int o = 128; o > 0; o >>= 1) {
    if (t < o) s[t] += s[t + o];
    __syncthreads();
  }
  if (t == 0) part[blockIdx.x] = s[0];
}

__global__ void k_scan2(int* part, int nb, int* csroff, int N, int E) {
  if (threadIdx.x == 0 && blockIdx.x == 0) {
    int run = 0;
    for (int b = 0; b < nb; ++b) { int v = part[b]; part[b] = run; run += v; }
    csroff[N] = E;
  }
}

__global__ void k_scan3(const int* __restrict__ cnt, const int* __restrict__ part,
                        int* __restrict__ csroff, int* __restrict__ cursor, int N) {
  __shared__ int s[256];
  int t = threadIdx.x, idx = blockIdx.x * 256 + t;
  int v = idx < N ? cnt[idx] : 0;
  s[t] = v;
  __syncthreads();
  for (int o = 1; o < 256; o <<= 1) {  // Hillis-Steele inclusive scan
    int add = t >= o ? s[t - o] : 0;
    __syncthreads();
    s[t] += add;
    __syncthreads();
  }
  if (idx < N) {
    int ex = part[blockIdx.x] + s[t] - v;  // exclusive
    csroff[idx] = ex;
    cursor[idx] = ex;
  }
}

__global__ void k_scatter(const int* __restrict__ ei, const float* __restrict__ dis,
                          int* __restrict__ cursor, int* __restrict__ csrsrc,
                          float* __restrict__ csrw, int E) {
  int e = blockIdx.x * 256 + threadIdx.x;
  if (e >= E) return;
  int s = ei[e];          // src
  int d = ei[E + e];      // dst
  int pos = atomicAdd(&cursor[d], 1);
  csrsrc[pos] = s;
  csrw[pos] = -dis[d] * dis[s];
}

// ----------------- converts -----------------
__global__ void k_convx(const float* __restrict__ x, u16* __restrict__ C, int N, int NPAD) {
  int t = blockIdx.x * 256 + threadIdx.x;
  int row = t >> 6;
  if (row >= NPAD) return;
  int c0 = (t & 63) * 8;
  u16x8 o;
  if (row < N) {
    const float4* p = (const float4*)(x + (size_t)row * 512 + c0);
    float4 a = p[0], b = p[1];
    o[0] = f2b(a.x); o[1] = f2b(a.y); o[2] = f2b(a.z); o[3] = f2b(a.w);
    o[4] = f2b(b.x); o[5] = f2b(b.y); o[6] = f2b(b.z); o[7] = f2b(b.w);
  } else {
#pragma unroll
    for (int j = 0; j < 8; ++j) o[j] = 0;
  }
  *(u16x8*)(C + (size_t)row * 1536 + c0) = o;
}

// Wb[n][ck*Kpad + k] = W[ck][k][n] (bf16, zero-padded)
__global__ void k_convw(const float* __restrict__ W, u16* __restrict__ Wb,
                        int Fin, int Kpad, int Nout) {
  int n = blockIdx.x;
  int ldw = 3 * Kpad;
  for (int kk = threadIdx.x; kk < ldw; kk += 256) {
    int ck = kk / Kpad, k = kk - ck * Kpad;
    float v = (k < Fin && n < Nout) ? W[((size_t)ck * Fin + k) * Nout + n] : 0.f;
    Wb[(size_t)n * ldw + kk] = f2b(v);
  }
}

// ----------------- SpMM (CSR gather, one wave per dst row) -----------------
template <int FV> struct UV;
template <> struct UV<8> { using T = u16x8; };
template <> struct UV<4> { using T = u16x4; };

// O[i] = alpha*(sum_e w_e * G[src_e] + diag_i*G[i]) - (Hs ? Hs[i] : 0)
// diag_i = -1 iff deg==0 (dis[i]==0), else 0.
template <int FV>
__global__ __launch_bounds__(256) void spmm_k(
    const u16* __restrict__ G, const u16* __restrict__ Hs, u16* __restrict__ O, int ld,
    const int* __restrict__ off, const int* __restrict__ srcs, const float* __restrict__ wv,
    const float* __restrict__ dis, float alpha, int N) {
  using uvec = typename UV<FV>::T;
  int i = blockIdx.x * 4 + (threadIdx.x >> 6);
  if (i >= N) return;
  int c0 = (threadIdx.x & 63) * FV;
  float acc[FV];
#pragma unroll
  for (int j = 0; j < FV; ++j) acc[j] = 0.f;
  const int e1 = off[i + 1];
  for (int e = off[i]; e < e1; ++e) {
    int s = srcs[e];
    float w = wv[e];
    uvec v = *(const uvec*)(G + (size_t)s * ld + c0);
#pragma unroll
    for (int j = 0; j < FV; ++j) acc[j] += w * b2f(v[j]);
  }
  if (dis[i] == 0.f) {  // isolated node: diag_w = -1
    uvec v = *(const uvec*)(G + (size_t)i * ld + c0);
#pragma unroll
    for (int j = 0; j < FV; ++j) acc[j] -= b2f(v[j]);
  }
  uvec o;
  if (Hs) {
    uvec h = *(const uvec*)(Hs + (size_t)i * ld + c0);
#pragma unroll
    for (int j = 0; j < FV; ++j) o[j] = f2b(alpha * acc[j] - b2f(h[j]));
  } else {
#pragma unroll
    for (int j = 0; j < FV; ++j) o[j] = f2b(acc[j]);
  }
  *(uvec*)(O + (size_t)i * ld + c0) = o;
}

// ----------------- GEMM: C = relu(A @ B^T + bias) -----------------
// A: [Mpad][lda] bf16 row-major (rows = nodes, K contiguous)
// B: [Npad][ldb] bf16 row-major (row n holds column n of weights, K contiguous)
// 128x128 tile, BK=64, 4 waves (2x2), 16x16x32 MFMA, global_load_lds staging.
template <typename OUTT>
__global__ __launch_bounds__(256) void gemm_k(
    const u16* __restrict__ A, int lda,
    const u16* __restrict__ B, int ldb,
    const float* __restrict__ bias,
    OUTT* __restrict__ C, int ldc,
    int K, int Nout, int Nrows) {
  __shared__ u16 As[128 * 64];
  __shared__ u16 Bs[128 * 64];
  const int tid = threadIdx.x;
  const int w = tid >> 6, l = tid & 63;
  const int m0 = blockIdx.x * 128, n0 = blockIdx.y * 128;

  // staging: thread covers 16B; LDS dest = c*4096B + w*1024B + lane*16B
  const int srow = w * 8 + (l >> 3);
  const int scol = (l & 7) * 8;
  const u16* ga = A + (size_t)m0 * lda + scol;
  const u16* gb = B + (size_t)n0 * ldb + scol;
  u16* lAs = &As[w * 512];
  u16* lBs = &Bs[w * 512];

  f32x4 acc[4][4];
#pragma unroll
  for (int m = 0; m < 4; ++m)
#pragma unroll
    for (int n = 0; n < 4; ++n) acc[m][n] = (f32x4){0.f, 0.f, 0.f, 0.f};

  const int wr = (w >> 1) * 64, wc = (w & 1) * 64;
  const int tr = l & 15, tg = l >> 4;

  for (int k0 = 0; k0 < K; k0 += 64) {
    __syncthreads();
#pragma unroll
    for (int c = 0; c < 4; ++c) {
      gload16(ga + (size_t)(srow + c * 32) * lda + k0, lAs + c * 2048);
      gload16(gb + (size_t)(srow + c * 32) * ldb + k0, lBs + c * 2048);
    }
    __syncthreads();
#pragma unroll
    for (int kk = 0; kk < 64; kk += 32) {
      s16x8 af[4], bf[4];
#pragma unroll
      for (int m = 0; m < 4; ++m)
        af[m] = *(const s16x8*)&As[(wr + m * 16 + tr) * 64 + kk + tg * 8];
#pragma unroll
      for (int n = 0; n < 4; ++n)
        bf[n] = *(const s16x8*)&Bs[(wc + n * 16 + tr) * 64 + kk + tg * 8];
#pragma unroll
      for (int m = 0; m < 4; ++m)
#pragma unroll
        for (int n = 0; n < 4; ++n)
          acc[m][n] = __builtin_amdgcn_mfma_f32_16x16x32_bf16(af[m], bf[n], acc[m][n], 0, 0, 0);
    }
  }

  // epilogue: bias + relu; C/D layout: col = lane&15, row = (lane>>4)*4 + j
#pragma unroll
  for (int m = 0; m < 4; ++m) {
    const int gr0 = m0 + wr + m * 16 + tg * 4;
#pragma unroll
    for (int n = 0; n < 4; ++n) {
      const int gc = n0 + wc + n * 16 + tr;
      const float bv = (gc < Nout) ? bias[gc] : 0.f;
#pragma unroll
      for (int j = 0; j < 4; ++j) {
        float v = acc[m][n][j] + bv;
        v = v > 0.f ? v : 0.f;
        if constexpr (sizeof(OUTT) == 2) {
          // bf16 out: pad cols MUST be zero (they feed next layer's K); pad rows free
          C[(size_t)(gr0 + j) * ldc + gc] = (gc < Nout) ? f2b(v) : (u16)0;
        } else {
          if (gr0 + j < Nrows && gc < Nout)
            C[(size_t)(gr0 + j) * ldc + gc] = v;
        }
      }
    }
  }
}

// ----------------- launch -----------------
extern "C" void kernel_launch(void* const* d_in, const int* in_sizes, int n_in,
                              void* d_out, int out_size, void* d_ws, size_t ws_size,
                              hipStream_t stream) {
  const float* x = (const float*)d_in[0];
  const int* ei = (const int*)d_in[1];
  const float* w1 = (const float*)d_in[2];
  const float* b1 = (const float*)d_in[3];
  const float* w2 = (const float*)d_in[4];
  const float* b2 = (const float*)d_in[5];
  const float* w3 = (const float*)d_in[6];
  const float* b3 = (const float*)d_in[7];
  float* out = (float*)d_out;

  const int N = in_sizes[0] / 512;      // 50000
  const int E = in_sizes[1] / 2;        // 1600000
  const int NPAD = ((N + 127) / 128) * 128;  // 50048
  const int NB = (N + 255) / 256;       // scan blocks
  const int EB = (E + 255) / 256;
  const int MT = NPAD / 128;            // 391 M-tiles

  char* ws = (char*)d_ws;
  size_t o = 0;
  auto alloc = [&](size_t b) -> void* {
    void* p = ws + o;
    o = (o + b + 255) & ~(size_t)255;
    return p;
  };
  int* cnt = (int*)alloc((size_t)N * 4);
  float* dis = (float*)alloc((size_t)N * 4);
  int* csroff = (int*)alloc((size_t)(N + 1) * 4);
  int* cursor = (int*)alloc((size_t)N * 4);
  int* part = (int*)alloc(1024);
  int* csrsrc = (int*)alloc((size_t)E * 4);
  float* csrw = (float*)alloc((size_t)E * 4);
  u16* CA = (u16*)alloc((size_t)NPAD * 1536 * 2);  // [H|T1|T2] Kpad=512
  u16* CB = (u16*)alloc((size_t)NPAD * 768 * 2);   // [H|T1|T2] Kpad=256
  u16* Wb = (u16*)alloc((size_t)1024 * 1536 * 2);
  (void)ws_size; (void)n_in; (void)out_size;

  // ---- graph normalization + CSR (by dst) ----
  k_zero_i32<<<NB, 256, 0, stream>>>(cnt, N);
  k_hist<<<EB, 256, 0, stream>>>(ei, cnt, E);
  k_dis<<<NB, 256, 0, stream>>>(cnt, dis, N);
  k_scan1<<<NB, 256, 0, stream>>>(cnt, part, N);
  k_scan2<<<1, 64, 0, stream>>>(part, NB, csroff, N, E);
  k_scan3<<<NB, 256, 0, stream>>>(cnt, part, csroff, cursor, N);
  k_scatter<<<EB, 256, 0, stream>>>(ei, dis, cursor, csrsrc, csrw, E);

  const int SG = (N + 3) / 4;  // spmm grid (4 waves = 4 rows per block)

  // ---- layer 1: 512 -> 250 (Kpad=512, stride 1536) ----
  k_convx<<<NPAD / 4, 256, 0, stream>>>(x, CA, N, NPAD);
  k_convw<<<256, 256, 0, stream>>>(w1, Wb, 512, 512, 250);
  spmm_k<8><<<SG, 256, 0, stream>>>(CA, (const u16*)nullptr, CA + 512, 1536,
                                    csroff, csrsrc, csrw, dis, 1.f, N);
  spmm_k<8><<<SG, 256, 0, stream>>>(CA + 512, CA, CA + 1024, 1536,
                                    csroff, csrsrc, csrw, dis, 2.f, N);
  gemm_k<u16><<<dim3(MT, 2), 256, 0, stream>>>(CA, 1536, Wb, 1536, b1,
                                               CB, 768, 1536, 250, N);

  // ---- layer 2: 250 -> 500 (Kpad=256, stride 768) ----
  k_convw<<<512, 256, 0, stream>>>(w2, Wb, 250, 256, 500);
  spmm_k<4><<<SG, 256, 0, stream>>>(CB, (const u16*)nullptr, CB + 256, 768,
                                    csroff, csrsrc, csrw, dis, 1.f, N);
  spmm_k<4><<<SG, 256, 0, stream>>>(CB + 256, CB, CB + 512, 768,
                                    csroff, csrsrc, csrw, dis, 2.f, N);
  gemm_k<u16><<<dim3(MT, 4), 256, 0, stream>>>(CB, 768, Wb, 768, b2,
                                               CA, 1536, 768, 500, N);

  // ---- layer 3: 500 -> 1000 (Kpad=512, stride 1536) ----
  k_convw<<<1024, 256, 0, stream>>>(w3, Wb, 500, 512, 1000);
  spmm_k<8><<<SG, 256, 0, stream>>>(CA, (const u16*)nullptr, CA + 512, 1536,
                                    csroff, csrsrc, csrw, dis, 1.f, N);
  spmm_k<8><<<SG, 256, 0, stream>>>(CA + 512, CA, CA + 1024, 1536,
                                    csroff, csrsrc, csrw, dis, 2.f, N);
  gemm_k<float><<<dim3(MT, 8), 256, 0, stream>>>(CA, 1536, Wb, 1536, b3,
                                                 out, 1000, 1536, 1000, N);
}